// Round 6
// baseline (17606.126 us; speedup 1.0000x reference)
//
#include <hip/hip_runtime.h>
#include <math.h>

// IDE state-space Kalman filter, MI355X (gfx950). Round 6:
// - trinv via recursive doubling (3 levels x 2 phases, was 7 x 2)
// - Pn*v mean-update partials folded into Pn-acc tile (MG phase deleted);
//   uses symmetry of Sinv*P so no r2/inv_r2 scaling needed
// - everything else from R5: column-split 4x4 matmuls, chol lookahead with
//   wave0 register chol16+inverse, nll in private registers

#define SQ 64
#define DQ 128
#define TQ 128
#define BQ 16
#define LDP 132           // padded LDS row stride (floats); rows 16B-aligned
#define NTH 1024
#define LOG2PI 1.8378770664093454f

#define SMEM_FLOATS 38544

__device__ __forceinline__ float block_reduce_sum(float v, float* red) {
  #pragma unroll
  for (int off = 32; off > 0; off >>= 1) v += __shfl_down(v, off);
  const int tid = threadIdx.x;
  if ((tid & 63) == 0) red[tid >> 6] = v;
  __syncthreads();
  v = 0.0f;
  #pragma unroll
  for (int w = 0; w < NTH / 64; w++) v += red[w];
  __syncthreads();
  return v;
}

// 16x16 Cholesky + lower-triangular inverse, register-resident on wave 0.
// Writes L to lower of the diag block, 1/Ljj to mdiag, strict part of
// Ldiag^{-1} transposed into the upper triangle of the diag block.
__device__ __forceinline__ void chol16(float* __restrict__ Wm,
                                       float* __restrict__ mdiag,
                                       int b0, int lane) {
  float a[16];
  if (lane < 16) {
    const float4* rp = (const float4*)(Wm + (b0 + lane) * LDP + b0);
    float4 q0 = rp[0], q1 = rp[1], q2v = rp[2], q3 = rp[3];
    a[0]=q0.x; a[1]=q0.y; a[2]=q0.z; a[3]=q0.w;
    a[4]=q1.x; a[5]=q1.y; a[6]=q1.z; a[7]=q1.w;
    a[8]=q2v.x; a[9]=q2v.y; a[10]=q2v.z; a[11]=q2v.w;
    a[12]=q3.x; a[13]=q3.y; a[14]=q3.z; a[15]=q3.w;
  } else {
    #pragma unroll
    for (int i = 0; i < 16; i++) a[i] = 1.0f;
  }
  float myrinv = 1.0f;
  #pragma unroll
  for (int j = 0; j < 16; j++) {
    float dj = __shfl(a[j], j);
    float rinv = rsqrtf(dj);
    float lij = a[j] * rinv;
    a[j] = lij;
    if (lane == j) myrinv = rinv;
    #pragma unroll
    for (int k = j + 1; k < 16; k++) {
      float lkj = __shfl(lij, k);
      a[k] = fmaf(-lij, lkj, a[k]);
    }
  }
  if (lane < 16) {
    float4* rp = (float4*)(Wm + (b0 + lane) * LDP + b0);
    rp[0] = make_float4(a[0], a[1], a[2], a[3]);
    rp[1] = make_float4(a[4], a[5], a[6], a[7]);
    rp[2] = make_float4(a[8], a[9], a[10], a[11]);
    rp[3] = make_float4(a[12], a[13], a[14], a[15]);
    mdiag[b0 + lane] = myrinv;
  }
  // inverse: lane c computes column c of Ldiag^{-1}
  float x[16];
  #pragma unroll
  for (int i = 0; i < 16; i++) {
    float s = (i == lane) ? 1.0f : 0.0f;
    #pragma unroll
    for (int k = 0; k < 16; k++) {
      if (k < i) {
        float Lik = __shfl(a[k], i);
        s = fmaf(-Lik, x[k], s);
      }
    }
    float ri = __shfl(myrinv, i);
    x[i] = (i < lane) ? 0.0f : s * ri;
  }
  if (lane < 16) {
    #pragma unroll
    for (int i = 0; i < 16; i++)
      if (i > lane) Wm[(b0 + lane) * LDP + (b0 + i)] = x[i];
  }
}

extern "C" __global__ __launch_bounds__(NTH, 4)
void ide_kf_kernel(const float* __restrict__ z_seq,
                   const float* __restrict__ site_lon,
                   const float* __restrict__ site_lat,
                   const float* __restrict__ mu_seq,
                   const float* __restrict__ sigma_seq,
                   const float* __restrict__ log_q,
                   const float* __restrict__ log_r,
                   const float* __restrict__ log_p0,
                   const float* __restrict__ log_damp,
                   const float* __restrict__ init_mean,
                   const float* __restrict__ coupling_raw,
                   float* __restrict__ ws) {
  extern __shared__ float smem[];
  float* Pm     = smem;                  // 128*132
  float* Wm     = Pm + DQ * LDP;         // 128*132
  float* gtmp   = Wm + DQ * LDP;         // 4096
  float* coords = gtmp + 4096;           // 128
  float* mv     = coords + 128;          // 128
  float* vv     = mv + DQ;               // 128
  float* yv     = vv + DQ;               // 128
  float* mdiag  = yv + DQ;               // 128
  float* red    = mdiag + DQ;            // 16

  const int tid = threadIdx.x;
  const int lane = tid & 63;
  const int b = blockIdx.x;
  float* nll_out = ws;

  const float r2 = __expf(2.0f * log_r[0]);
  const float q2 = __expf(2.0f * log_q[0]);
  const float p0sq = __expf(2.0f * log_p0[0]);
  const float damping = __expf(log_damp[0]);
  const float cpl00 = 1.0f + 0.25f * tanhf(coupling_raw[0]);
  const float cpl01 = 0.25f * tanhf(coupling_raw[1]);
  const float cpl10 = 0.25f * tanhf(coupling_raw[2]);
  const float cpl11 = 1.0f + 0.25f * tanhf(coupling_raw[3]);

  const int z = tid >> 9, t9 = tid & 511;
  const int cg = t9 & 15, rg = t9 >> 4;
  const int r0 = rg * 4, c0 = z * 64 + cg * 4;

  // ---- lon/lat projection ----
  float myLon = (tid < SQ) ? site_lon[tid] : 0.0f;
  float myLat = (tid < SQ) ? site_lat[tid] : 0.0f;
  float lat0 = block_reduce_sum(myLat, red) * (1.0f / 64.0f);
  float lon0 = block_reduce_sum(myLon, red) * (1.0f / 64.0f);
  if (tid < SQ) {
    const float km = 111.32f;
    float cs = cosf(lat0 * 0.017453292519943295f);
    coords[2 * tid]     = (myLon - lon0) * (km * cs);
    coords[2 * tid + 1] = (myLat - lat0) * km;
  }
  __syncthreads();
  float dsum = 0.0f, dcnt = 0.0f;
  for (int idx = tid; idx < SQ * SQ; idx += NTH) {
    int i = idx >> 6, j = idx & 63;
    float dx = coords[2 * i] - coords[2 * j];
    float dy = coords[2 * i + 1] - coords[2 * j + 1];
    float d = sqrtf(dx * dx + dy * dy + 1e-12f);
    dsum += d;
    if (d > 1e-6f) dcnt += 1.0f;
  }
  dsum = block_reduce_sum(dsum, red);
  dcnt = block_reduce_sum(dcnt, red);
  float scale = dsum / fmaxf(dcnt, 1.0f);
  float sdiv = 1.0f / fmaxf(scale, 1e-6f);
  if (tid < SQ) { coords[2 * tid] *= sdiv; coords[2 * tid + 1] *= sdiv; }

  // ---- init: Pm = p0sq I, Wm = (p0sq+r2) I, mv = init_mean ----
  for (int e = tid; e < (DQ * LDP) / 4; e += NTH) {
    ((float4*)Pm)[e] = make_float4(0.0f, 0.0f, 0.0f, 0.0f);
    ((float4*)Wm)[e] = make_float4(0.0f, 0.0f, 0.0f, 0.0f);
  }
  __syncthreads();
  if (tid < DQ) {
    Pm[tid * LDP + tid] = p0sq;
    Wm[tid * LDP + tid] = p0sq + r2;
    mv[tid] = init_mean[tid];
  }
  __syncthreads();

  float nllp = 0.0f;   // private nll partial (quad + logdet pieces)

  #pragma unroll 1
  for (int t = 0; t < TQ; t++) {
    const float* zt = z_seq + ((size_t)b * TQ + t) * DQ;

    if (t > 0) {
      const float* mu_t = mu_seq + ((size_t)b * (TQ - 1) + (t - 1)) * 4;
      const float* sg_t = sigma_seq + ((size_t)b * (TQ - 1) + (t - 1)) * 16;

      // ---- PHASE A: finish m-update (merge 32 partials) + build A ----
      if (tid < DQ) {
        float s = 0.0f;
        const float* gp = gtmp + tid * 32;
        #pragma unroll
        for (int u = 0; u < 32; u += 4) {
          float4 g4 = *(const float4*)&gp[u];
          s += g4.x + g4.y + g4.z + g4.w;
        }
        mv[tid] += s;
      }
      {
        const int unit = tid >> 2, q = tid & 3;
        const int r = unit >> 1, ss = unit & 1, tt = r >> 6, i = r & 63;
        float m0 = mu_t[0], m1 = mu_t[1], m2 = mu_t[2], m3 = mu_t[3];
        float dmx, dmy, c00, c01, c11;
        if (tt == 0 && ss == 0) {
          dmx = m0; dmy = m1;
          c00 = sg_t[0]; c01 = 0.5f * (sg_t[1] + sg_t[4]); c11 = sg_t[5];
        } else if (tt == 1 && ss == 1) {
          dmx = m2; dmy = m3;
          c00 = sg_t[10]; c01 = 0.5f * (sg_t[11] + sg_t[14]); c11 = sg_t[15];
        } else {
          dmx = 0.5f * (m0 + m2); dmy = 0.5f * (m1 + m3);
          float s00 = sg_t[0];
          float s02 = 0.5f * (sg_t[2] + sg_t[8]);
          float s22 = sg_t[10];
          float s01 = 0.5f * (sg_t[1] + sg_t[4]);
          float s03 = 0.5f * (sg_t[3] + sg_t[12]);
          float s21 = 0.5f * (sg_t[9] + sg_t[6]);
          float s23 = 0.5f * (sg_t[11] + sg_t[14]);
          float s11 = sg_t[5];
          float s13 = 0.5f * (sg_t[7] + sg_t[13]);
          float s33 = sg_t[15];
          c00 = 0.25f * (s00 + s02 + s02 + s22);
          c01 = 0.25f * (s01 + s03 + s21 + s23);
          c11 = 0.25f * (s11 + s13 + s13 + s33);
        }
        float D00 = 1.0001f + 2.0f * c00;
        float D01 = 2.0f * c01;
        float D11 = 1.0001f + 2.0f * c11;
        float det = D00 * D11 - D01 * D01;
        float dinv = 1.0f / det;
        float d00 = D11 * dinv, d01 = -D01 * dinv, d11 = D00 * dinv;
        float ldts = __logf(det);
        float cix = coords[2 * i], ciy = coords[2 * i + 1];
        const float* cj = coords + q * 32;
        float kv[16];
        float rsum = 0.0f;
        #pragma unroll
        for (int u = 0; u < 16; u++) {
          float dx = cix - cj[2 * u] - dmx;
          float dy = ciy - cj[2 * u + 1] - dmy;
          float qf = d00 * dx * dx + 2.0f * d01 * dx * dy + d11 * dy * dy;
          kv[u] = __expf(-0.5f * (qf + ldts));
          rsum += kv[u];
        }
        float rtot = rsum + __shfl_xor(rsum, 1);
        rtot += __shfl_xor(rtot, 2);
        float cv = (tt == 0) ? ((ss == 0) ? cpl00 : cpl01)
                             : ((ss == 0) ? cpl10 : cpl11);
        float norm = cv / fmaxf(rtot, 1e-6f);
        #pragma unroll
        for (int u = 0; u < 16; u++) kv[u] *= norm;
        if (ss == tt && ((i >> 4) == q)) kv[i & 15] += 1.0f - damping;
        float* wrow = Wm + r * LDP + ss * 64 + q * 16;
        #pragma unroll
        for (int u4 = 0; u4 < 4; u4++)
          *(float4*)&wrow[u4 * 4] =
              make_float4(kv[u4*4], kv[u4*4+1], kv[u4*4+2], kv[u4*4+3]);
      }
      __syncthreads();

      // ---- PHASE T-acc: acc = A*P (4x4, full k) + m=A*m fold ----
      {
        float acc[4][4];
        #pragma unroll
        for (int i = 0; i < 4; i++)
          #pragma unroll
          for (int j = 0; j < 4; j++) acc[i][j] = 0.0f;
        float newm = 0.0f;
        if (tid < DQ) {
          const float* arow = Wm + tid * LDP;
          float s = 0.0f;
          for (int k = 0; k < DQ; k += 4) {
            float4 a4 = *(const float4*)&arow[k];
            float4 m4 = *(const float4*)&mv[k];
            s = fmaf(a4.x, m4.x, s); s = fmaf(a4.y, m4.y, s);
            s = fmaf(a4.z, m4.z, s); s = fmaf(a4.w, m4.w, s);
          }
          newm = s;
        }
        for (int c = 0; c < 32; c++) {
          const int k = c * 4;
          float4 A0 = *(const float4*)&Wm[(r0 + 0) * LDP + k];
          float4 A1 = *(const float4*)&Wm[(r0 + 1) * LDP + k];
          float4 A2 = *(const float4*)&Wm[(r0 + 2) * LDP + k];
          float4 A3 = *(const float4*)&Wm[(r0 + 3) * LDP + k];
          float av[4][4] = {{A0.x,A0.y,A0.z,A0.w},{A1.x,A1.y,A1.z,A1.w},
                            {A2.x,A2.y,A2.z,A2.w},{A3.x,A3.y,A3.z,A3.w}};
          #pragma unroll
          for (int kk = 0; kk < 4; kk++) {
            float4 p4 = *(const float4*)&Pm[(k + kk) * LDP + c0];
            float pa[4] = {p4.x, p4.y, p4.z, p4.w};
            #pragma unroll
            for (int i = 0; i < 4; i++)
              #pragma unroll
              for (int j = 0; j < 4; j++)
                acc[i][j] = fmaf(av[i][kk], pa[j], acc[i][j]);
          }
        }
        __syncthreads();
        // ---- PHASE T-write: Pm = T^T ----
        if (tid < DQ) mv[tid] = newm;
        #pragma unroll
        for (int j = 0; j < 4; j++)
          *(float4*)&Pm[(c0 + j) * LDP + r0] =
              make_float4(acc[0][j], acc[1][j], acc[2][j], acc[3][j]);
        __syncthreads();
      }

      // ---- PHASE P-acc: acc = A * T^T (= A P A^T, symmetric) ----
      {
        float acc[4][4];
        #pragma unroll
        for (int i = 0; i < 4; i++)
          #pragma unroll
          for (int j = 0; j < 4; j++) acc[i][j] = 0.0f;
        for (int c = 0; c < 32; c++) {
          const int k = c * 4;
          float4 A0 = *(const float4*)&Wm[(r0 + 0) * LDP + k];
          float4 A1 = *(const float4*)&Wm[(r0 + 1) * LDP + k];
          float4 A2 = *(const float4*)&Wm[(r0 + 2) * LDP + k];
          float4 A3 = *(const float4*)&Wm[(r0 + 3) * LDP + k];
          float av[4][4] = {{A0.x,A0.y,A0.z,A0.w},{A1.x,A1.y,A1.z,A1.w},
                            {A2.x,A2.y,A2.z,A2.w},{A3.x,A3.y,A3.z,A3.w}};
          #pragma unroll
          for (int kk = 0; kk < 4; kk++) {
            float4 p4 = *(const float4*)&Pm[(k + kk) * LDP + c0];
            float pa[4] = {p4.x, p4.y, p4.z, p4.w};
            #pragma unroll
            for (int i = 0; i < 4; i++)
              #pragma unroll
              for (int j = 0; j < 4; j++)
                acc[i][j] = fmaf(av[i][kk], pa[j], acc[i][j]);
          }
        }
        __syncthreads();
        // ---- PHASE P-write: Pm = P'+q2 I ; Wm = P'+(q2+r2) I ----
        #pragma unroll
        for (int i = 0; i < 4; i++) {
          const int rr = r0 + i;
          float4 v4 = make_float4(acc[i][0], acc[i][1], acc[i][2], acc[i][3]);
          float4 w4 = v4;
          if (rr >= c0 && rr < c0 + 4) {
            if (rr == c0)     { v4.x += q2; w4.x += q2 + r2; }
            if (rr == c0 + 1) { v4.y += q2; w4.y += q2 + r2; }
            if (rr == c0 + 2) { v4.z += q2; w4.z += q2 + r2; }
            if (rr == c0 + 3) { v4.w += q2; w4.w += q2 + r2; }
          }
          *(float4*)&Pm[rr * LDP + c0] = v4;
          *(float4*)&Wm[rr * LDP + c0] = w4;
        }
        __syncthreads();
      }
    }

    // ================= measurement update =================
    // ---- PHASE K0: wave0 factor+invert diag 0 ; vv compute ----
    if (tid < 64) {
      chol16(Wm, mdiag, 0, lane);
    } else if (tid < 192) {
      const int i = tid - 64;
      vv[i] = zt[i] - mv[i];
    }
    __syncthreads();

    // ---- chol with lookahead ----
    #pragma unroll 1
    for (int kb = 0; kb < 7; kb++) {
      const int b0k = kb * 16, base = b0k + 16, nbelow = DQ - base;
      // PHASE KP: panel rows (row-per-thread, race-free)
      if (tid < nbelow) {
        const int r = base + tid;
        float* wr = Wm + r * LDP + b0k;
        float w[16];
        #pragma unroll
        for (int u4 = 0; u4 < 4; u4++) {
          float4 w4 = *(const float4*)&wr[u4 * 4];
          w[u4*4] = w4.x; w[u4*4+1] = w4.y; w[u4*4+2] = w4.z; w[u4*4+3] = w4.w;
        }
        float out[16];
        #pragma unroll
        for (int j = 0; j < 16; j++) {
          float s = w[j] * mdiag[b0k + j];
          #pragma unroll
          for (int l = 0; l < 16; l++) {
            if (l < j) s = fmaf(w[l], Wm[(b0k + l) * LDP + b0k + j], s);
          }
          out[j] = s;
        }
        #pragma unroll
        for (int u4 = 0; u4 < 4; u4++)
          *(float4*)&wr[u4 * 4] =
              make_float4(out[u4*4], out[u4*4+1], out[u4*4+2], out[u4*4+3]);
      }
      __syncthreads();
      // PHASE KT: wave0 updates+factors+inverts diag kb+1 || trailing rest
      if (tid < 64) {
        #pragma unroll
        for (int u = 0; u < 4; u++) {
          const int o = lane * 4 + u;
          const int mr = o >> 4, mc = o & 15;
          if (mr >= mc) {
            const float* pi = Wm + (base + mr) * LDP + b0k;
            const float* pj = Wm + (base + mc) * LDP + b0k;
            float s = 0.0f;
            #pragma unroll
            for (int c4 = 0; c4 < 4; c4++) {
              float4 xa = *(const float4*)&pi[c4 * 4];
              float4 yb = *(const float4*)&pj[c4 * 4];
              s = fmaf(xa.x, yb.x, s); s = fmaf(xa.y, yb.y, s);
              s = fmaf(xa.z, yb.z, s); s = fmaf(xa.w, yb.w, s);
            }
            Wm[(base + mr) * LDP + base + mc] -= s;
          }
        }
        chol16(Wm, mdiag, base, lane);
      } else if (tid >= 256) {
        const int grp = (tid >> 8) - 1;      // 0..2
        const int t8 = tid & 255;
        const int mrow = t8 >> 4, mcol = t8 & 15;
        const int mb = 7 - kb;
        int cnt = 0;
        for (int bi = 0; bi < mb; bi++) {
          for (int bj = 0; bj <= bi; bj++) {
            if (bi | bj) {
              if (cnt % 3 == grp && (bi > bj || mrow >= mcol)) {
                const int i = base + bi * 16 + mrow;
                const int j = base + bj * 16 + mcol;
                const float* pi = Wm + i * LDP + b0k;
                const float* pj = Wm + j * LDP + b0k;
                float s = 0.0f;
                #pragma unroll
                for (int c4 = 0; c4 < 4; c4++) {
                  float4 xa = *(const float4*)&pi[c4 * 4];
                  float4 yb = *(const float4*)&pj[c4 * 4];
                  s = fmaf(xa.x, yb.x, s); s = fmaf(xa.y, yb.y, s);
                  s = fmaf(xa.z, yb.z, s); s = fmaf(xa.w, yb.w, s);
                }
                Wm[i * LDP + j] -= s;
              }
              cnt++;
            }
          }
        }
      }
      __syncthreads();
    }

    // ---- trinv: recursive doubling, M into transposed-upper storage ----
    // Level 0: s=16, 4 merges (p=32m), one output per thread
    {
      const int m = tid >> 8, i = (tid >> 4) & 15, j = tid & 15;
      const int p = m * 32;
      const float* Lrow = Wm + (p + 16 + i) * LDP + p;
      float g = Lrow[j] * mdiag[p + j];
      for (int k = j + 1; k < 16; k++)
        g = fmaf(Lrow[k], Wm[(p + j) * LDP + (p + k)], g);
      gtmp[m * 256 + i * 16 + j] = g;
    }
    __syncthreads();
    {
      const int m = tid >> 8, i = (tid >> 4) & 15, j = tid & 15;
      const int p = m * 32;
      const float* gb = gtmp + m * 256;
      float s = mdiag[p + 16 + i] * gb[i * 16 + j];
      for (int k = 0; k < i; k++)
        s = fmaf(Wm[(p + 16 + k) * LDP + (p + 16 + i)], gb[k * 16 + j], s);
      Wm[(p + j) * LDP + (p + 16 + i)] = -s;
    }
    __syncthreads();
    // Level 1: s=32, 2 merges (p=64m), two outputs per thread
    {
      const int m = tid >> 9, rem = tid & 511;
      const int i0 = rem >> 5, j = rem & 31;
      const int p = m * 64;
      #pragma unroll
      for (int h = 0; h < 2; h++) {
        const int i = i0 + h * 16;
        const float* Lrow = Wm + (p + 32 + i) * LDP + p;
        float g = Lrow[j] * mdiag[p + j];
        for (int k = j + 1; k < 32; k++)
          g = fmaf(Lrow[k], Wm[(p + j) * LDP + (p + k)], g);
        gtmp[m * 1024 + i * 32 + j] = g;
      }
    }
    __syncthreads();
    {
      const int m = tid >> 9, rem = tid & 511;
      const int i0 = rem >> 5, j = rem & 31;
      const int p = m * 64;
      const float* gb = gtmp + m * 1024;
      float out[2];
      #pragma unroll
      for (int h = 0; h < 2; h++) {
        const int i = i0 + h * 16;
        float s = mdiag[p + 32 + i] * gb[i * 32 + j];
        for (int k = 0; k < i; k++)
          s = fmaf(Wm[(p + 32 + k) * LDP + (p + 32 + i)], gb[k * 32 + j], s);
        out[h] = -s;
      }
      #pragma unroll
      for (int h = 0; h < 2; h++)
        Wm[(p + j) * LDP + (p + 32 + i0 + h * 16)] = out[h];
    }
    __syncthreads();
    // Level 2: s=64, 1 merge (p=0), four outputs per thread
    {
      const int i0 = tid >> 6, j = tid & 63;
      #pragma unroll
      for (int h = 0; h < 4; h++) {
        const int i = i0 + h * 16;
        const float* Lrow = Wm + (64 + i) * LDP;
        float g = Lrow[j] * mdiag[j];
        for (int k = j + 1; k < 64; k++)
          g = fmaf(Lrow[k], Wm[j * LDP + k], g);
        gtmp[i * 64 + j] = g;
      }
    }
    __syncthreads();
    {
      const int i0 = tid >> 6, j = tid & 63;
      float out[4];
      #pragma unroll
      for (int h = 0; h < 4; h++) {
        const int i = i0 + h * 16;
        float s = mdiag[64 + i] * gtmp[i * 64 + j];
        for (int k = 0; k < i; k++)
          s = fmaf(Wm[(64 + k) * LDP + (64 + i)], gtmp[k * 64 + j], s);
        out[h] = -s;
      }
      #pragma unroll
      for (int h = 0; h < 4; h++)
        Wm[j * LDP + (64 + i0 + h * 16)] = out[h];
    }
    __syncthreads();

    // ---- PHASE Y-acc: Y = M*P (triangular k<=row) + y=Mv + logdet fold ----
    {
      float acc[4][4];
      #pragma unroll
      for (int i = 0; i < 4; i++)
        #pragma unroll
        for (int j = 0; j < 4; j++) acc[i][j] = 0.0f;
      if (tid < DQ) {
        nllp -= __logf(mdiag[tid]);          // 0.5*logdet contribution
        float s = mdiag[tid] * vv[tid];
        for (int k = 0; k < tid; k++) s = fmaf(Wm[k * LDP + tid], vv[k], s);
        yv[tid] = s;
      }
      for (int c = 0; c < rg; c++) {
        const int k = c * 4;
        #pragma unroll
        for (int kk = 0; kk < 4; kk++) {
          float4 cv4 = *(const float4*)&Wm[(k + kk) * LDP + r0];
          float4 p4  = *(const float4*)&Pm[(k + kk) * LDP + c0];
          float cva[4] = {cv4.x, cv4.y, cv4.z, cv4.w};
          float pa[4]  = {p4.x, p4.y, p4.z, p4.w};
          #pragma unroll
          for (int i = 0; i < 4; i++)
            #pragma unroll
            for (int j = 0; j < 4; j++)
              acc[i][j] = fmaf(cva[i], pa[j], acc[i][j]);
        }
      }
      #pragma unroll
      for (int kk = 0; kk < 4; kk++) {
        float4 cv4 = *(const float4*)&Wm[(r0 + kk) * LDP + r0];
        float4 p4  = *(const float4*)&Pm[(r0 + kk) * LDP + c0];
        float cva[4] = {cv4.x, cv4.y, cv4.z, cv4.w};
        float pa[4]  = {p4.x, p4.y, p4.z, p4.w};
        #pragma unroll
        for (int i = 0; i < 4; i++) {
          float coef = (kk < i) ? cva[i] : ((kk == i) ? mdiag[r0 + i] : 0.0f);
          #pragma unroll
          for (int j = 0; j < 4; j++)
            acc[i][j] = fmaf(coef, pa[j], acc[i][j]);
        }
      }
      __syncthreads();
      #pragma unroll
      for (int i = 0; i < 4; i++)
        *(float4*)&Pm[(r0 + i) * LDP + c0] =
            make_float4(acc[i][0], acc[i][1], acc[i][2], acc[i][3]);
      __syncthreads();
    }

    // ---- PHASE Pn-acc: Pn = r2*M^T*Y (k>=row) + quad fold + m-partials ----
    {
      float acc[4][4];
      #pragma unroll
      for (int i = 0; i < 4; i++)
        #pragma unroll
        for (int j = 0; j < 4; j++) acc[i][j] = 0.0f;
      if (z == 1 && t9 >= 384) {
        const int i = t9 - 384;
        float s = mdiag[i] * yv[i];
        for (int k = i + 1; k < DQ; k++)
          s = fmaf(Wm[i * LDP + k], yv[k], s);
        nllp += 0.5f * vv[i] * s;            // 0.5*quad contribution
      }
      {
        float av[4][4];
        #pragma unroll
        for (int i = 0; i < 4; i++) {
          float4 a4 = *(const float4*)&Wm[(r0 + i) * LDP + r0];
          av[i][0] = a4.x; av[i][1] = a4.y; av[i][2] = a4.z; av[i][3] = a4.w;
        }
        #pragma unroll
        for (int kk = 0; kk < 4; kk++) {
          float4 p4 = *(const float4*)&Pm[(r0 + kk) * LDP + c0];
          float pa[4] = {p4.x, p4.y, p4.z, p4.w};
          #pragma unroll
          for (int i = 0; i < 4; i++) {
            float coef = (kk > i) ? av[i][kk]
                       : ((kk == i) ? mdiag[r0 + i] : 0.0f);
            #pragma unroll
            for (int j = 0; j < 4; j++)
              acc[i][j] = fmaf(coef, pa[j], acc[i][j]);
          }
        }
      }
      for (int c = rg + 1; c < 32; c++) {
        const int k = c * 4;
        float4 A0 = *(const float4*)&Wm[(r0 + 0) * LDP + k];
        float4 A1 = *(const float4*)&Wm[(r0 + 1) * LDP + k];
        float4 A2 = *(const float4*)&Wm[(r0 + 2) * LDP + k];
        float4 A3 = *(const float4*)&Wm[(r0 + 3) * LDP + k];
        float av[4][4] = {{A0.x,A0.y,A0.z,A0.w},{A1.x,A1.y,A1.z,A1.w},
                          {A2.x,A2.y,A2.z,A2.w},{A3.x,A3.y,A3.z,A3.w}};
        #pragma unroll
        for (int kk = 0; kk < 4; kk++) {
          float4 p4 = *(const float4*)&Pm[(k + kk) * LDP + c0];
          float pa[4] = {p4.x, p4.y, p4.z, p4.w};
          #pragma unroll
          for (int i = 0; i < 4; i++)
            #pragma unroll
            for (int j = 0; j < 4; j++)
              acc[i][j] = fmaf(av[i][kk], pa[j], acc[i][j]);
        }
      }
      // fold: m-update partials. Sinv*P is symmetric, so
      // (P*Sinv*v)[r] = (Sinv*P*v)[r] = (acc_unscaled * v)[r] row-wise.
      {
        float4 vvs = *(const float4*)&vv[c0];
        #pragma unroll
        for (int i = 0; i < 4; i++) {
          float s = acc[i][0] * vvs.x + acc[i][1] * vvs.y
                  + acc[i][2] * vvs.z + acc[i][3] * vvs.w;
          gtmp[(r0 + i) * 32 + (z * 16 + cg)] = s;
        }
      }
      __syncthreads();
      #pragma unroll
      for (int i = 0; i < 4; i++)
        *(float4*)&Pm[(r0 + i) * LDP + c0] =
            make_float4(r2 * acc[i][0], r2 * acc[i][1],
                        r2 * acc[i][2], r2 * acc[i][3]);
      __syncthreads();
    }
  }

  float total = block_reduce_sum(nllp, red);
  if (tid == 0)
    nll_out[b] = total + (float)TQ * 0.5f * (float)DQ * LOG2PI;
}

extern "C" __global__ void ide_finalize(const float* __restrict__ part,
                                        float* __restrict__ out) {
  if (threadIdx.x == 0) {
    float s = 0.0f;
    for (int i = 0; i < BQ; i++) s += part[i];
    out[0] = s * (1.0f / BQ);
  }
}

extern "C" void kernel_launch(void* const* d_in, const int* in_sizes, int n_in,
                              void* d_out, int out_size, void* d_ws, size_t ws_size,
                              hipStream_t stream) {
  (void)in_sizes; (void)n_in; (void)out_size; (void)ws_size;
  const float* z_seq        = (const float*)d_in[0];
  const float* site_lon     = (const float*)d_in[1];
  const float* site_lat     = (const float*)d_in[2];
  const float* mu_seq       = (const float*)d_in[3];
  const float* sigma_seq    = (const float*)d_in[4];
  const float* log_q        = (const float*)d_in[5];
  const float* log_r        = (const float*)d_in[6];
  const float* log_p0       = (const float*)d_in[7];
  const float* log_damp     = (const float*)d_in[8];
  const float* init_mean    = (const float*)d_in[9];
  const float* coupling_raw = (const float*)d_in[10];
  float* ws = (float*)d_ws;
  float* out = (float*)d_out;

  const size_t smem_bytes = (size_t)SMEM_FLOATS * sizeof(float);
  hipFuncSetAttribute((const void*)ide_kf_kernel,
                      hipFuncAttributeMaxDynamicSharedMemorySize,
                      (int)smem_bytes);

  hipLaunchKernelGGL(ide_kf_kernel, dim3(BQ), dim3(NTH), smem_bytes, stream,
                     z_seq, site_lon, site_lat, mu_seq, sigma_seq,
                     log_q, log_r, log_p0, log_damp, init_mean, coupling_raw,
                     ws);
  hipLaunchKernelGGL(ide_finalize, dim3(1), dim3(64), 0, stream, ws, out);
}

// Round 7
// 14680.505 us; speedup vs baseline: 1.1993x; 1.1993x over previous
//
#include <hip/hip_runtime.h>
#include <math.h>

// IDE state-space Kalman filter, MI355X (gfx950). Round 7:
// - the four 128^3 matmuls (T=A*P, P'=T*A^T, Y=M*P, Pn=M^T*Y) moved to
//   v_mfma_f32_16x16x32_bf16 (per-wave 4 C-tiles). fp32 kept for Sm/chol/
//   trinv/logdet/GEMVs. P carried in bf16 between steps.
// - buffer time-sharing: W region = Tb(bf16) -> Sm/L/M(fp32) -> M^T+Y^T(bf16)
// - trinv reverted to R5 diagonal-distance (R6 doubling regressed)

#define SQ 64
#define DQ 128
#define TQ 128
#define BQ 16
#define LDP 132           // fp32 row stride
#define LDB 136           // bf16 row stride (16B-aligned rows, 2-way banks)
#define WFLOATS 17408     // W region: 69632 B (holds 2 bf16 matrices)
#define NTH 1024
#define LOG2PI 1.8378770664093454f

#define SMEM_FLOATS 37520

typedef __attribute__((ext_vector_type(8))) short bf16x8;
typedef __attribute__((ext_vector_type(4))) float f32x4;

__device__ __forceinline__ unsigned short f2bf(float f) {
  unsigned u = __float_as_uint(f);
  u += 0x7fffu + ((u >> 16) & 1u);
  return (unsigned short)(u >> 16);
}
__device__ __forceinline__ float bf2f(unsigned short h) {
  return __uint_as_float(((unsigned)h) << 16);
}
__device__ __forceinline__ uint4 pack8(const float* v) {
  uint4 r;
  r.x = (unsigned)f2bf(v[0]) | ((unsigned)f2bf(v[1]) << 16);
  r.y = (unsigned)f2bf(v[2]) | ((unsigned)f2bf(v[3]) << 16);
  r.z = (unsigned)f2bf(v[4]) | ((unsigned)f2bf(v[5]) << 16);
  r.w = (unsigned)f2bf(v[6]) | ((unsigned)f2bf(v[7]) << 16);
  return r;
}

__device__ __forceinline__ float block_reduce_sum(float v, float* red) {
  #pragma unroll
  for (int off = 32; off > 0; off >>= 1) v += __shfl_down(v, off);
  const int tid = threadIdx.x;
  if ((tid & 63) == 0) red[tid >> 6] = v;
  __syncthreads();
  v = 0.0f;
  #pragma unroll
  for (int w = 0; w < NTH / 64; w++) v += red[w];
  __syncthreads();
  return v;
}

// 16x16 Cholesky + triangular inverse on wave 0 (register/shfl resident).
__device__ __forceinline__ void chol16(float* __restrict__ Wf,
                                       float* __restrict__ mdiag,
                                       int b0, int lane) {
  float a[16];
  if (lane < 16) {
    const float4* rp = (const float4*)(Wf + (b0 + lane) * LDP + b0);
    float4 q0 = rp[0], q1 = rp[1], q2v = rp[2], q3 = rp[3];
    a[0]=q0.x; a[1]=q0.y; a[2]=q0.z; a[3]=q0.w;
    a[4]=q1.x; a[5]=q1.y; a[6]=q1.z; a[7]=q1.w;
    a[8]=q2v.x; a[9]=q2v.y; a[10]=q2v.z; a[11]=q2v.w;
    a[12]=q3.x; a[13]=q3.y; a[14]=q3.z; a[15]=q3.w;
  } else {
    #pragma unroll
    for (int i = 0; i < 16; i++) a[i] = 1.0f;
  }
  float myrinv = 1.0f;
  #pragma unroll
  for (int j = 0; j < 16; j++) {
    float dj = __shfl(a[j], j);
    float rinv = rsqrtf(dj);
    float lij = a[j] * rinv;
    a[j] = lij;
    if (lane == j) myrinv = rinv;
    #pragma unroll
    for (int k = j + 1; k < 16; k++) {
      float lkj = __shfl(lij, k);
      a[k] = fmaf(-lij, lkj, a[k]);
    }
  }
  if (lane < 16) {
    float4* rp = (float4*)(Wf + (b0 + lane) * LDP + b0);
    rp[0] = make_float4(a[0], a[1], a[2], a[3]);
    rp[1] = make_float4(a[4], a[5], a[6], a[7]);
    rp[2] = make_float4(a[8], a[9], a[10], a[11]);
    rp[3] = make_float4(a[12], a[13], a[14], a[15]);
    mdiag[b0 + lane] = myrinv;
  }
  float x[16];
  #pragma unroll
  for (int i = 0; i < 16; i++) {
    float s = (i == lane) ? 1.0f : 0.0f;
    #pragma unroll
    for (int k = 0; k < 16; k++) {
      if (k < i) {
        float Lik = __shfl(a[k], i);
        s = fmaf(-Lik, x[k], s);
      }
    }
    float ri = __shfl(myrinv, i);
    x[i] = (i < lane) ? 0.0f : s * ri;
  }
  if (lane < 16) {
    #pragma unroll
    for (int i = 0; i < 16; i++)
      if (i > lane) Wf[(b0 + lane) * LDP + (b0 + i)] = x[i];
  }
}

extern "C" __global__ __launch_bounds__(NTH, 4)
void ide_kf_kernel(const float* __restrict__ z_seq,
                   const float* __restrict__ site_lon,
                   const float* __restrict__ site_lat,
                   const float* __restrict__ mu_seq,
                   const float* __restrict__ sigma_seq,
                   const float* __restrict__ log_q,
                   const float* __restrict__ log_r,
                   const float* __restrict__ log_p0,
                   const float* __restrict__ log_damp,
                   const float* __restrict__ init_mean,
                   const float* __restrict__ coupling_raw,
                   float* __restrict__ ws) {
  extern __shared__ float smem[];
  float* Wf     = smem;                  // 17408 floats (fp32 chol space)
  float* B1f    = Wf + WFLOATS;          // 8704 floats (Ab / Mb bf16)
  float* B2f    = B1f + 8704;            // 8704 floats (Pb bf16)
  float* gtmp   = B2f + 8704;            // 2048
  float* coords = gtmp + 2048;           // 128
  float* mv     = coords + 128;          // 128
  float* vv     = mv + DQ;               // 128
  float* yv     = vv + DQ;               // 128
  float* mdiag  = yv + DQ;               // 128
  float* red    = mdiag + DQ;            // 16

  unsigned short* Tb  = (unsigned short*)Wf;            // bf16, stride LDB
  unsigned short* Mtb = (unsigned short*)Wf;            // M^T row-major bf16
  unsigned short* Yt  = (unsigned short*)Wf + 17408;    // Y^T bf16
  unsigned short* Ab  = (unsigned short*)B1f;           // A bf16
  unsigned short* Mb  = (unsigned short*)B1f;           // M row-major bf16
  unsigned short* Pb  = (unsigned short*)B2f;           // P bf16 (symmetric)

  const int tid = threadIdx.x;
  const int lane = tid & 63;
  const int wave = tid >> 6;
  const int rb = wave >> 1, ch = wave & 1;
  const int m16 = lane & 15, quad = lane >> 4;
  const int b = blockIdx.x;
  float* nll_out = ws;

  const float r2 = __expf(2.0f * log_r[0]);
  const float q2 = __expf(2.0f * log_q[0]);
  const float p0sq = __expf(2.0f * log_p0[0]);
  const float damping = __expf(log_damp[0]);
  const float cpl00 = 1.0f + 0.25f * tanhf(coupling_raw[0]);
  const float cpl01 = 0.25f * tanhf(coupling_raw[1]);
  const float cpl10 = 0.25f * tanhf(coupling_raw[2]);
  const float cpl11 = 1.0f + 0.25f * tanhf(coupling_raw[3]);

  // ---- lon/lat projection ----
  float myLon = (tid < SQ) ? site_lon[tid] : 0.0f;
  float myLat = (tid < SQ) ? site_lat[tid] : 0.0f;
  float lat0 = block_reduce_sum(myLat, red) * (1.0f / 64.0f);
  float lon0 = block_reduce_sum(myLon, red) * (1.0f / 64.0f);
  if (tid < SQ) {
    const float km = 111.32f;
    float cs = cosf(lat0 * 0.017453292519943295f);
    coords[2 * tid]     = (myLon - lon0) * (km * cs);
    coords[2 * tid + 1] = (myLat - lat0) * km;
  }
  __syncthreads();
  float dsum = 0.0f, dcnt = 0.0f;
  for (int idx = tid; idx < SQ * SQ; idx += NTH) {
    int i = idx >> 6, j = idx & 63;
    float dx = coords[2 * i] - coords[2 * j];
    float dy = coords[2 * i + 1] - coords[2 * j + 1];
    float d = sqrtf(dx * dx + dy * dy + 1e-12f);
    dsum += d;
    if (d > 1e-6f) dcnt += 1.0f;
  }
  dsum = block_reduce_sum(dsum, red);
  dcnt = block_reduce_sum(dcnt, red);
  float scale = dsum / fmaxf(dcnt, 1.0f);
  float sdiv = 1.0f / fmaxf(scale, 1e-6f);
  if (tid < SQ) { coords[2 * tid] *= sdiv; coords[2 * tid + 1] *= sdiv; }

  // ---- init: Pb = bf16(p0sq I), Wf = (p0sq+r2) I, mv = init_mean ----
  for (int e = tid; e < WFLOATS / 4; e += NTH)
    ((float4*)Wf)[e] = make_float4(0.0f, 0.0f, 0.0f, 0.0f);
  for (int e = tid; e < 8704 / 4; e += NTH)
    ((float4*)B2f)[e] = make_float4(0.0f, 0.0f, 0.0f, 0.0f);
  __syncthreads();
  if (tid < DQ) {
    Wf[tid * LDP + tid] = p0sq + r2;
    Pb[tid * LDB + tid] = f2bf(p0sq);
    mv[tid] = init_mean[tid];
  }
  __syncthreads();

  float nllp = 0.0f;

  #pragma unroll 1
  for (int t = 0; t < TQ; t++) {
    const float* zt = z_seq + ((size_t)b * TQ + t) * DQ;

    if (t > 0) {
      const float* mu_t = mu_seq + ((size_t)b * (TQ - 1) + (t - 1)) * 4;
      const float* sg_t = sigma_seq + ((size_t)b * (TQ - 1) + (t - 1)) * 16;

      // ---- PHASE A: merge m-update partials + build A -> Ab (bf16) ----
      if (tid < DQ) {
        float s = gtmp[2 * tid] + gtmp[2 * tid + 1];
        #pragma unroll
        for (int rb8 = 0; rb8 < 8; rb8++) s += gtmp[256 + tid * 8 + rb8];
        mv[tid] += s;
      }
      {
        const int unit = tid >> 2, q = tid & 3;
        const int r = unit >> 1, ss = unit & 1, tt = r >> 6, i = r & 63;
        float m0 = mu_t[0], m1 = mu_t[1], m2 = mu_t[2], m3 = mu_t[3];
        float dmx, dmy, c00, c01, c11;
        if (tt == 0 && ss == 0) {
          dmx = m0; dmy = m1;
          c00 = sg_t[0]; c01 = 0.5f * (sg_t[1] + sg_t[4]); c11 = sg_t[5];
        } else if (tt == 1 && ss == 1) {
          dmx = m2; dmy = m3;
          c00 = sg_t[10]; c01 = 0.5f * (sg_t[11] + sg_t[14]); c11 = sg_t[15];
        } else {
          dmx = 0.5f * (m0 + m2); dmy = 0.5f * (m1 + m3);
          float s00 = sg_t[0];
          float s02 = 0.5f * (sg_t[2] + sg_t[8]);
          float s22 = sg_t[10];
          float s01 = 0.5f * (sg_t[1] + sg_t[4]);
          float s03 = 0.5f * (sg_t[3] + sg_t[12]);
          float s21 = 0.5f * (sg_t[9] + sg_t[6]);
          float s23 = 0.5f * (sg_t[11] + sg_t[14]);
          float s11 = sg_t[5];
          float s13 = 0.5f * (sg_t[7] + sg_t[13]);
          float s33 = sg_t[15];
          c00 = 0.25f * (s00 + s02 + s02 + s22);
          c01 = 0.25f * (s01 + s03 + s21 + s23);
          c11 = 0.25f * (s11 + s13 + s13 + s33);
        }
        float D00 = 1.0001f + 2.0f * c00;
        float D01 = 2.0f * c01;
        float D11 = 1.0001f + 2.0f * c11;
        float det = D00 * D11 - D01 * D01;
        float dinv = 1.0f / det;
        float d00 = D11 * dinv, d01 = -D01 * dinv, d11 = D00 * dinv;
        float ldts = __logf(det);
        float cix = coords[2 * i], ciy = coords[2 * i + 1];
        const float* cj = coords + q * 32;
        float kv[16];
        float rsum = 0.0f;
        #pragma unroll
        for (int u = 0; u < 16; u++) {
          float dx = cix - cj[2 * u] - dmx;
          float dy = ciy - cj[2 * u + 1] - dmy;
          float qf = d00 * dx * dx + 2.0f * d01 * dx * dy + d11 * dy * dy;
          kv[u] = __expf(-0.5f * (qf + ldts));
          rsum += kv[u];
        }
        float rtot = rsum + __shfl_xor(rsum, 1);
        rtot += __shfl_xor(rtot, 2);
        float cv = (tt == 0) ? ((ss == 0) ? cpl00 : cpl01)
                             : ((ss == 0) ? cpl10 : cpl11);
        float norm = cv / fmaxf(rtot, 1e-6f);
        #pragma unroll
        for (int u = 0; u < 16; u++) kv[u] *= norm;
        if (ss == tt && ((i >> 4) == q)) kv[i & 15] += 1.0f - damping;
        unsigned short* arow = Ab + r * LDB + ss * 64 + q * 16;
        *(uint4*)(arow) = pack8(kv);
        *(uint4*)(arow + 8) = pack8(kv + 8);
      }
      __syncthreads();

      // ---- PHASE T: mfma T = A*P (full) + m = A*m GEMV ----
      {
        f32x4 acc[4];
        #pragma unroll
        for (int c = 0; c < 4; c++) acc[c] = (f32x4){0.0f, 0.0f, 0.0f, 0.0f};
        #pragma unroll
        for (int ks = 0; ks < 4; ks++) {
          const int ko = 32 * ks + 8 * quad;
          bf16x8 a = *(const bf16x8*)(Ab + (16 * rb + m16) * LDB + ko);
          #pragma unroll
          for (int ct = 0; ct < 4; ct++) {
            bf16x8 bb = *(const bf16x8*)(Pb + (64 * ch + 16 * ct + m16) * LDB + ko);
            acc[ct] = __builtin_amdgcn_mfma_f32_16x16x32_bf16(a, bb, acc[ct], 0, 0, 0);
          }
        }
        float newm = 0.0f;
        if (tid < DQ) {
          const unsigned* ar = (const unsigned*)(Ab + tid * LDB);
          #pragma unroll 8
          for (int k2 = 0; k2 < 64; k2++) {
            unsigned p = ar[k2];
            newm = fmaf(__uint_as_float(p << 16), mv[2 * k2], newm);
            newm = fmaf(__uint_as_float(p & 0xffff0000u), mv[2 * k2 + 1], newm);
          }
        }
        __syncthreads();
        #pragma unroll
        for (int ct = 0; ct < 4; ct++)
          #pragma unroll
          for (int reg = 0; reg < 4; reg++)
            Tb[(16 * rb + 4 * quad + reg) * LDB + 64 * ch + 16 * ct + m16] =
                f2bf(acc[ct][reg]);
        if (tid < DQ) mv[tid] = newm;
        __syncthreads();
      }

      // ---- PHASE P': mfma P' = T*A^T (lower tiles) -> Wf fp32 + Pb bf16 ----
      {
        const int ctmax = rb - 4 * ch;
        f32x4 acc[4];
        #pragma unroll
        for (int c = 0; c < 4; c++) acc[c] = (f32x4){0.0f, 0.0f, 0.0f, 0.0f};
        if (ctmax >= 0) {
          #pragma unroll
          for (int ks = 0; ks < 4; ks++) {
            const int ko = 32 * ks + 8 * quad;
            bf16x8 a = *(const bf16x8*)(Tb + (16 * rb + m16) * LDB + ko);
            #pragma unroll
            for (int ct = 0; ct < 4; ct++) {
              if (ct <= ctmax) {
                bf16x8 bb = *(const bf16x8*)(Ab + (64 * ch + 16 * ct + m16) * LDB + ko);
                acc[ct] = __builtin_amdgcn_mfma_f32_16x16x32_bf16(a, bb, acc[ct], 0, 0, 0);
              }
            }
          }
        }
        __syncthreads();
        #pragma unroll
        for (int ct = 0; ct < 4; ct++) {
          if (ct <= ctmax) {
            const bool strict = (ct < ctmax);
            #pragma unroll
            for (int reg = 0; reg < 4; reg++) {
              const int rg = 16 * rb + 4 * quad + reg;
              const int cgl = 64 * ch + 16 * ct + m16;
              float v = acc[ct][reg];
              float pv = v + ((rg == cgl) ? q2 : 0.0f);
              float wv = v + ((rg == cgl) ? (q2 + r2) : 0.0f);
              Pb[rg * LDB + cgl] = f2bf(pv);
              Wf[rg * LDP + cgl] = wv;
              if (strict) {
                Pb[cgl * LDB + rg] = f2bf(pv);
                Wf[cgl * LDP + rg] = v;
              }
            }
          }
        }
        __syncthreads();
      }
    }

    // ================= measurement update =================
    // ---- PHASE K0: wave0 chol diag0 ; vv ----
    if (tid < 64) {
      chol16(Wf, mdiag, 0, lane);
    } else if (tid < 192) {
      const int i = tid - 64;
      vv[i] = zt[i] - mv[i];
    }
    __syncthreads();

    // ---- chol with lookahead (R5) ----
    #pragma unroll 1
    for (int kb = 0; kb < 7; kb++) {
      const int b0k = kb * 16, base = b0k + 16, nbelow = DQ - base;
      if (tid < nbelow) {
        const int r = base + tid;
        float* wr = Wf + r * LDP + b0k;
        float w[16];
        #pragma unroll
        for (int u4 = 0; u4 < 4; u4++) {
          float4 w4 = *(const float4*)&wr[u4 * 4];
          w[u4*4] = w4.x; w[u4*4+1] = w4.y; w[u4*4+2] = w4.z; w[u4*4+3] = w4.w;
        }
        float out[16];
        #pragma unroll
        for (int j = 0; j < 16; j++) {
          float s = w[j] * mdiag[b0k + j];
          #pragma unroll
          for (int l = 0; l < 16; l++) {
            if (l < j) s = fmaf(w[l], Wf[(b0k + l) * LDP + b0k + j], s);
          }
          out[j] = s;
        }
        #pragma unroll
        for (int u4 = 0; u4 < 4; u4++)
          *(float4*)&wr[u4 * 4] =
              make_float4(out[u4*4], out[u4*4+1], out[u4*4+2], out[u4*4+3]);
      }
      __syncthreads();
      if (tid < 64) {
        #pragma unroll
        for (int u = 0; u < 4; u++) {
          const int o = lane * 4 + u;
          const int mr = o >> 4, mc = o & 15;
          if (mr >= mc) {
            const float* pi = Wf + (base + mr) * LDP + b0k;
            const float* pj = Wf + (base + mc) * LDP + b0k;
            float s = 0.0f;
            #pragma unroll
            for (int c4 = 0; c4 < 4; c4++) {
              float4 xa = *(const float4*)&pi[c4 * 4];
              float4 yb = *(const float4*)&pj[c4 * 4];
              s = fmaf(xa.x, yb.x, s); s = fmaf(xa.y, yb.y, s);
              s = fmaf(xa.z, yb.z, s); s = fmaf(xa.w, yb.w, s);
            }
            Wf[(base + mr) * LDP + base + mc] -= s;
          }
        }
        chol16(Wf, mdiag, base, lane);
      } else if (tid >= 256) {
        const int grp = (tid >> 8) - 1;
        const int t8 = tid & 255;
        const int mrow = t8 >> 4, mcol = t8 & 15;
        const int mb = 7 - kb;
        int cnt = 0;
        for (int bi = 0; bi < mb; bi++) {
          for (int bj = 0; bj <= bi; bj++) {
            if (bi | bj) {
              if (cnt % 3 == grp && (bi > bj || mrow >= mcol)) {
                const int i = base + bi * 16 + mrow;
                const int j = base + bj * 16 + mcol;
                const float* pi = Wf + i * LDP + b0k;
                const float* pj = Wf + j * LDP + b0k;
                float s = 0.0f;
                #pragma unroll
                for (int c4 = 0; c4 < 4; c4++) {
                  float4 xa = *(const float4*)&pi[c4 * 4];
                  float4 yb = *(const float4*)&pj[c4 * 4];
                  s = fmaf(xa.x, yb.x, s); s = fmaf(xa.y, yb.y, s);
                  s = fmaf(xa.z, yb.z, s); s = fmaf(xa.w, yb.w, s);
                }
                Wf[i * LDP + j] -= s;
              }
              cnt++;
            }
          }
        }
      }
      __syncthreads();
    }

    // ---- trinv (R5 diagonal-distance): M into transposed-upper of Wf ----
    #pragma unroll 1
    for (int d = 1; d < 8; d++) {
      const int z4 = tid >> 8;
      const int t8 = tid & 255;
      const int i16 = t8 >> 4, j16 = t8 & 15;
      for (int nb = z4; nb + d < 8; nb += 4) {
        const int J = nb, I = nb + d;
        const float* Lrow = Wf + (I * 16 + i16) * LDP + J * 16;
        const float* Mrow = Wf + (J * 16 + j16) * LDP + J * 16;
        const float md = mdiag[J * 16 + j16];
        float g = 0.0f;
        #pragma unroll
        for (int c4 = 0; c4 < 4; c4++) {
          float4 lv = *(const float4*)&Lrow[c4 * 4];
          float4 mq = *(const float4*)&Mrow[c4 * 4];
          float w0 = (c4*4+0 > j16) ? mq.x : ((c4*4+0 == j16) ? md : 0.0f);
          float w1 = (c4*4+1 > j16) ? mq.y : ((c4*4+1 == j16) ? md : 0.0f);
          float w2 = (c4*4+2 > j16) ? mq.z : ((c4*4+2 == j16) ? md : 0.0f);
          float w3 = (c4*4+3 > j16) ? mq.w : ((c4*4+3 == j16) ? md : 0.0f);
          g = fmaf(lv.x, w0, g); g = fmaf(lv.y, w1, g);
          g = fmaf(lv.z, w2, g); g = fmaf(lv.w, w3, g);
        }
        for (int K = J + 1; K < I; K++) {
          const float* LK = Lrow + (K - J) * 16;
          const float* MK = Wf + (J * 16 + j16) * LDP + K * 16;
          #pragma unroll
          for (int c4 = 0; c4 < 4; c4++) {
            float4 lv = *(const float4*)&LK[c4 * 4];
            float4 mq = *(const float4*)&MK[c4 * 4];
            g = fmaf(lv.x, mq.x, g); g = fmaf(lv.y, mq.y, g);
            g = fmaf(lv.z, mq.z, g); g = fmaf(lv.w, mq.w, g);
          }
        }
        gtmp[nb * 256 + t8] = g;
      }
      __syncthreads();
      for (int nb = z4; nb + d < 8; nb += 4) {
        const int J = nb, I = nb + d;
        const float* gb = gtmp + nb * 256;
        float s = mdiag[I * 16 + i16] * gb[i16 * 16 + j16];
        for (int k = 0; k < i16; k++)
          s = fmaf(Wf[(I * 16 + k) * LDP + I * 16 + i16], gb[k * 16 + j16], s);
        Wf[(J * 16 + j16) * LDP + (I * 16 + i16)] = -s;
      }
      __syncthreads();
    }

    // ---- PHASE MC: y=Mv + logdet fold; convert M -> Mb & Mtb (staged) ----
    {
      const int mrow = tid >> 3, kc = (tid & 7) * 16;
      float mtv[16], mbv[16];
      #pragma unroll
      for (int u = 0; u < 16; u++) {
        const int k = kc + u;
        mtv[u] = (k > mrow) ? Wf[mrow * LDP + k]
               : ((k == mrow) ? mdiag[mrow] : 0.0f);
        mbv[u] = (k < mrow) ? Wf[k * LDP + mrow]
               : ((k == mrow) ? mdiag[mrow] : 0.0f);
      }
      if (tid < DQ) {
        nllp -= __logf(mdiag[tid]);
        float s = mdiag[tid] * vv[tid];
        for (int k = 0; k < tid; k++) s = fmaf(Wf[k * LDP + tid], vv[k], s);
        yv[tid] = s;
      }
      __syncthreads();
      unsigned short* mt = Mtb + mrow * LDB + kc;
      *(uint4*)(mt) = pack8(mtv);
      *(uint4*)(mt + 8) = pack8(mtv + 8);
      unsigned short* mb = Mb + mrow * LDB + kc;
      *(uint4*)(mb) = pack8(mbv);
      *(uint4*)(mb + 8) = pack8(mbv + 8);
      __syncthreads();
    }

    // ---- PHASE Y: mfma Y = M*P (k-blocks <= rb/2), write Y^T ----
    {
      f32x4 acc[4];
      #pragma unroll
      for (int c = 0; c < 4; c++) acc[c] = (f32x4){0.0f, 0.0f, 0.0f, 0.0f};
      const int ksmax = rb >> 1;
      for (int ks = 0; ks <= ksmax; ks++) {
        const int ko = 32 * ks + 8 * quad;
        bf16x8 a = *(const bf16x8*)(Mb + (16 * rb + m16) * LDB + ko);
        #pragma unroll
        for (int ct = 0; ct < 4; ct++) {
          bf16x8 bb = *(const bf16x8*)(Pb + (64 * ch + 16 * ct + m16) * LDB + ko);
          acc[ct] = __builtin_amdgcn_mfma_f32_16x16x32_bf16(a, bb, acc[ct], 0, 0, 0);
        }
      }
      __syncthreads();
      #pragma unroll
      for (int ct = 0; ct < 4; ct++)
        #pragma unroll
        for (int reg = 0; reg < 4; reg++)
          Yt[(64 * ch + 16 * ct + m16) * LDB + 16 * rb + 4 * quad + reg] =
              f2bf(acc[ct][reg]);
      __syncthreads();
    }

    // ---- PHASE Pn: mfma Pn = M^T*Y (lower tiles) + quad + m-fold ----
    {
      f32x4 acc[4];
      #pragma unroll
      for (int c = 0; c < 4; c++) acc[c] = (f32x4){0.0f, 0.0f, 0.0f, 0.0f};
      if (tid < DQ) nllp += 0.5f * yv[tid] * yv[tid];
      const int ctmax = rb - 4 * ch;
      if (ctmax >= 0) {
        for (int ks = (rb >> 1); ks < 4; ks++) {
          const int ko = 32 * ks + 8 * quad;
          bf16x8 a = *(const bf16x8*)(Mtb + (16 * rb + m16) * LDB + ko);
          #pragma unroll
          for (int ct = 0; ct < 4; ct++) {
            if (ct <= ctmax) {
              bf16x8 bb = *(const bf16x8*)(Yt + (64 * ch + 16 * ct + m16) * LDB + ko);
              acc[ct] = __builtin_amdgcn_mfma_f32_16x16x32_bf16(a, bb, acc[ct], 0, 0, 0);
            }
          }
        }
      }
      __syncthreads();
      // Pb = bf16(r2 * Pn), mirror strict tiles
      #pragma unroll
      for (int ct = 0; ct < 4; ct++) {
        if (ct <= ctmax) {
          const bool strict = (ct < ctmax);
          #pragma unroll
          for (int reg = 0; reg < 4; reg++) {
            const int rg = 16 * rb + 4 * quad + reg;
            const int cgl = 64 * ch + 16 * ct + m16;
            unsigned short hv = f2bf(r2 * acc[ct][reg]);
            Pb[rg * LDB + cgl] = hv;
            if (strict) Pb[cgl * LDB + rg] = hv;
          }
        }
      }
      // m-fold: (Sinv*P)*v row partials (unscaled acc; Sinv*P symmetric)
      {
        float s[4];
        #pragma unroll
        for (int reg = 0; reg < 4; reg++) {
          float tacc = 0.0f;
          #pragma unroll
          for (int ct = 0; ct < 4; ct++)
            if (ct <= ctmax)
              tacc += acc[ct][reg] * vv[64 * ch + 16 * ct + m16];
          #pragma unroll
          for (int off = 1; off < 16; off <<= 1) tacc += __shfl_xor(tacc, off);
          s[reg] = tacc;
        }
        if (m16 == 0) {
          #pragma unroll
          for (int reg = 0; reg < 4; reg++)
            gtmp[(16 * rb + 4 * quad + reg) * 2 + ch] = s[reg];
        }
        #pragma unroll
        for (int ct = 0; ct < 4; ct++) {
          float tacc = 0.0f;
          if (ct < ctmax) {   // strict-lower tiles only (avoid double count)
            #pragma unroll
            for (int reg = 0; reg < 4; reg++)
              tacc += acc[ct][reg] * vv[16 * rb + 4 * quad + reg];
          }
          tacc += __shfl_xor(tacc, 16);
          tacc += __shfl_xor(tacc, 32);
          if (quad == 0)
            gtmp[256 + (64 * ch + 16 * ct + m16) * 8 + rb] = tacc;
        }
      }
      __syncthreads();
    }
  }

  float total = block_reduce_sum(nllp, red);
  if (tid == 0)
    nll_out[b] = total + (float)TQ * 0.5f * (float)DQ * LOG2PI;
}

extern "C" __global__ void ide_finalize(const float* __restrict__ part,
                                        float* __restrict__ out) {
  if (threadIdx.x == 0) {
    float s = 0.0f;
    for (int i = 0; i < BQ; i++) s += part[i];
    out[0] = s * (1.0f / BQ);
  }
}

extern "C" void kernel_launch(void* const* d_in, const int* in_sizes, int n_in,
                              void* d_out, int out_size, void* d_ws, size_t ws_size,
                              hipStream_t stream) {
  (void)in_sizes; (void)n_in; (void)out_size; (void)ws_size;
  const float* z_seq        = (const float*)d_in[0];
  const float* site_lon     = (const float*)d_in[1];
  const float* site_lat     = (const float*)d_in[2];
  const float* mu_seq       = (const float*)d_in[3];
  const float* sigma_seq    = (const float*)d_in[4];
  const float* log_q        = (const float*)d_in[5];
  const float* log_r        = (const float*)d_in[6];
  const float* log_p0       = (const float*)d_in[7];
  const float* log_damp     = (const float*)d_in[8];
  const float* init_mean    = (const float*)d_in[9];
  const float* coupling_raw = (const float*)d_in[10];
  float* ws = (float*)d_ws;
  float* out = (float*)d_out;

  const size_t smem_bytes = (size_t)SMEM_FLOATS * sizeof(float);
  hipFuncSetAttribute((const void*)ide_kf_kernel,
                      hipFuncAttributeMaxDynamicSharedMemorySize,
                      (int)smem_bytes);

  hipLaunchKernelGGL(ide_kf_kernel, dim3(BQ), dim3(NTH), smem_bytes, stream,
                     z_seq, site_lon, site_lat, mu_seq, sigma_seq,
                     log_q, log_r, log_p0, log_damp, init_mean, coupling_raw,
                     ws);
  hipLaunchKernelGGL(ide_finalize, dim3(1), dim3(64), 0, stream, ws, out);
}